// Round 11
// baseline (191.450 us; speedup 1.0000x reference)
//
#include <hip/hip_runtime.h>
#include <math.h>

// x: (4,16,256,32,64) f32 -> NS=64 samples, CD=256 channels, HW=2048 positions
#define NS 64
#define CD 256
#define HW 2048
#define MD 1024
#define SAMPLE (CD * HW)
#define LN_EPS 1e-5f

#define PB 128           // positions per block (8 waves x 16-p strip)
#define MC 64            // m-chunk
#define NCH (MD / MC)    // 16 chunks

typedef float f32x4 __attribute__((ext_vector_type(4)));
typedef long i64;

// Rotated 4-bit XOR swizzle for Ysh (bits 3-6).
__device__ __forceinline__ int swz(int p) {
  int k = (p ^ (p >> 2)) & 15;
  return ((k & 7) << 4) | (k & 8);
}

__device__ __forceinline__ void gl_lds16(const unsigned char* g, unsigned char* l) {
  __builtin_amdgcn_global_load_lds(
      (const __attribute__((address_space(1))) unsigned char*)g,
      (__attribute__((address_space(3))) unsigned char*)l, 16, 0, 0);
}

// ---------------- weight prep: f32 -> fp8 e4m3, FRAGMENT-PACKED (MC=64) ----------------
// w_in8p frag g2 = ch*32 + mt*8 + kk  (ch 0..15, mt 0..3, kk 0..7):
//   byte g2*512 + l*8 + j = w_in[c = kk*32+(l>>4)*8+j][m = ch*64+mt*16+(l&15)]
// w_out8p frag g = ch*32 + ct*2 + ks  (ct 0..15, ks 0..1):
//   byte g*512 + l*8 + j  = w_out[m = ch*64+ks*32+(l>>4)*8+j][c = ct*16+(l&15)]
__global__ __launch_bounds__(256) void k_prep(const float* __restrict__ w_in,
                                              const float* __restrict__ w_out,
                                              unsigned char* __restrict__ w_in8p,
                                              unsigned char* __restrict__ w_out8p) {
  int id = blockIdx.x * 256 + threadIdx.x;  // 0..131071 (one int = 4 bytes each)
  if (id < 65536) {
    int i = id;
    int g2 = i >> 7, l = (i >> 1) & 63, j0 = (i & 1) * 4;
    int ch = g2 >> 5, mt = (g2 >> 3) & 3, kk = g2 & 7;
    int m = ch * 64 + mt * 16 + (l & 15);
    int c0 = kk * 32 + (l >> 4) * 8 + j0;
    float a = w_in[(size_t)(c0 + 0) * MD + m];
    float b = w_in[(size_t)(c0 + 1) * MD + m];
    float c = w_in[(size_t)(c0 + 2) * MD + m];
    float d = w_in[(size_t)(c0 + 3) * MD + m];
    int r = __builtin_amdgcn_cvt_pk_fp8_f32(a, b, 0, false);
    r = __builtin_amdgcn_cvt_pk_fp8_f32(c, d, r, true);
    ((int*)w_in8p)[i] = r;
  } else {
    int i = id - 65536;
    int g = i >> 7, l = (i >> 1) & 63, j0 = (i & 1) * 4;
    int ch = g >> 5, ct = (g >> 1) & 15, ks = g & 1;
    int c = ct * 16 + (l & 15);
    int m0 = ch * 64 + ks * 32 + (l >> 4) * 8 + j0;
    float a = w_out[(size_t)(m0 + 0) * CD + c];
    float b = w_out[(size_t)(m0 + 1) * CD + c];
    float cc = w_out[(size_t)(m0 + 2) * CD + c];
    float d = w_out[(size_t)(m0 + 3) * CD + c];
    int r = __builtin_amdgcn_cvt_pk_fp8_f32(a, b, 0, false);
    r = __builtin_amdgcn_cvt_pk_fp8_f32(cc, d, r, true);
    ((int*)w_out8p)[i] = r;
  }
}

// ---------------- LN stats, stage 1 ----------------
__global__ __launch_bounds__(256) void k_stats1(const float* __restrict__ x,
                                                double* __restrict__ partial) {
  int s = blockIdx.x >> 3, sl = blockIdx.x & 7;
  const float4* p = (const float4*)(x + (size_t)s * SAMPLE + (size_t)sl * 65536);
  double sum = 0.0, ssq = 0.0;
  for (int i = 0; i < 64; ++i) {
    float4 v = p[i * 256 + threadIdx.x];
    sum += (double)v.x + (double)v.y + (double)v.z + (double)v.w;
    ssq += (double)v.x * v.x + (double)v.y * v.y + (double)v.z * v.z + (double)v.w * v.w;
  }
  for (int off = 32; off; off >>= 1) {
    sum += __shfl_down(sum, off);
    ssq += __shfl_down(ssq, off);
  }
  __shared__ double red[4][2];
  int wv = threadIdx.x >> 6, ln = threadIdx.x & 63;
  if (ln == 0) { red[wv][0] = sum; red[wv][1] = ssq; }
  __syncthreads();
  if (threadIdx.x == 0) {
    for (int i = 1; i < 4; ++i) { sum += red[i][0]; ssq += red[i][1]; }
    partial[blockIdx.x * 2] = sum;
    partial[blockIdx.x * 2 + 1] = ssq;
  }
}

// ---------------- LN stats, stage 2 ----------------
__global__ void k_stats2(const double* __restrict__ partial, float* __restrict__ stats) {
  int s = threadIdx.x;  // 64 threads
  double sum = 0.0, ssq = 0.0;
  for (int i = 0; i < 8; ++i) {
    sum += partial[(s * 8 + i) * 2];
    ssq += partial[(s * 8 + i) * 2 + 1];
  }
  double mean = sum / (double)SAMPLE;
  double var = ssq / (double)SAMPLE - mean * mean;
  stats[s * 2] = (float)mean;
  stats[s * 2 + 1] = (float)(1.0 / sqrt(var + (double)LN_EPS));
}

// ---------------- fused LN + MLP + layer-scale + residual ----------------
// MC=64 (16 chunks, 16 barriers), enabled by Ysh-region reuse: after breg load
// Ysh is dead (the wave's whole slice lives in breg), so its 32KB becomes W2
// slots 1-2. LDS map (80KB, 2 blocks/CU):
//   [ 0K,16K) W2 slot0      [16K,48K) W2 slots1-2  == Ysh during staging
//   [48K,64K) W1 slot0      [64K,80K) W1 slot1
// Per iter: barrier; prefetch W1(ch+1)->slot (ch+1)&1, W2(ch+1)->slot (ch+1)%3;
// 64-MFMA burst (GEMM2(ch-1) 32 + GEMM1(ch) 32); GELU/shfl tail -> a2p[0..1]
// consumed next iter. Slot distinctness & WAR-across-barrier verified.
__global__ __launch_bounds__(512, 4) void k_fused(
    const float* __restrict__ x, const float* __restrict__ ln_w, const float* __restrict__ ln_b,
    const float* __restrict__ b_in, const float* __restrict__ b_out, const float* __restrict__ gamma,
    const unsigned char* __restrict__ w_in8p, const unsigned char* __restrict__ w_out8p,
    const float* __restrict__ stats, float* __restrict__ out) {
  extern __shared__ unsigned char smem[];
  unsigned char* Ysh = smem + 16384;   // [128][256] fp8 swizzled (staging only)

  const int tid = threadIdx.x;
  const int lane = tid & 63, l15 = lane & 15, l4 = lane >> 4;
  const int wv = tid >> 6;                 // 0..7
  const int s = blockIdx.x >> 4;
  const int p0 = (blockIdx.x & 15) * PB;
  const float mu = stats[s * 2], rstd = stats[s * 2 + 1];
  const float a_ln = rstd, c_ln = -mu * rstd;
  const size_t xbase = (size_t)s * SAMPLE;

  // ---- prefetch chunk-0 weights into the non-Ysh slots (hide under staging) ----
  // W1(0) -> slot0 @48K; W2(0) -> slot0 @0K. 16KB each = 2 gl_lds per wave.
  gl_lds16(w_in8p + wv * 2048 + lane * 16, smem + 49152 + wv * 2048);
  gl_lds16(w_in8p + wv * 2048 + 1024 + lane * 16, smem + 49152 + wv * 2048 + 1024);
  gl_lds16(w_out8p + wv * 2048 + lane * 16, smem + wv * 2048);
  gl_lds16(w_out8p + wv * 2048 + 1024 + lane * 16, smem + wv * 2048 + 1024);

  // ---- stage Ysh: normalize + affine, transpose (c,p)->(p,c), cvt fp8 ----
  #pragma unroll
  for (int it = 0; it < 4; ++it) {
    int bid = it * 512 + tid;               // 2048 4x4 micro-blocks
    int c0 = (bid >> 5) * 4, pp = (bid & 31) * 4;
    float yv[4][4];
    #pragma unroll
    for (int i = 0; i < 4; ++i) {
      size_t off = (size_t)(c0 + i) * HW + p0 + pp;
      float4 xv = *(const float4*)(x + xbase + off);
      float4 lw = *(const float4*)(ln_w + off);
      float4 lb = *(const float4*)(ln_b + off);
      yv[i][0] = fmaf(fmaf(xv.x, a_ln, c_ln), lw.x, lb.x);
      yv[i][1] = fmaf(fmaf(xv.y, a_ln, c_ln), lw.y, lb.y);
      yv[i][2] = fmaf(fmaf(xv.z, a_ln, c_ln), lw.z, lb.z);
      yv[i][3] = fmaf(fmaf(xv.w, a_ln, c_ln), lw.w, lb.w);
    }
    #pragma unroll
    for (int j = 0; j < 4; ++j) {
      int p = pp + j;
      int r = __builtin_amdgcn_cvt_pk_fp8_f32(yv[0][j], yv[1][j], 0, false);
      r = __builtin_amdgcn_cvt_pk_fp8_f32(yv[2][j], yv[3][j], r, true);
      *(int*)&Ysh[p * 256 + (c0 ^ swz(p))] = r;
    }
  }

  const int strip = wv * 16;               // wave's p-strip
  const int pY = strip + l15;              // Ysh row this lane reads
  const int sY = swz(pY);
  f32x4 acc2[16] = {};                     // 16p x 256c per wave (16 c-tiles)

  __syncthreads();  // Ysh visible; chunk-0 weight DMA drained

  // ---- breg: the wave's ENTIRE Ysh slice -> 8 i64 registers ----
  i64 breg[8];
  #pragma unroll
  for (int kk = 0; kk < 8; ++kk)
    breg[kk] = *(const i64*)&Ysh[pY * 256 + ((kk * 32 + l4 * 8) ^ sY)];

  __syncthreads();  // all breg reads done -> Ysh region may be overwritten by DMA

  i64 a2p0 = 0, a2p1 = 0;

  for (int ch = 0; ch < NCH; ++ch) {
    if (ch) __syncthreads();  // prev prefetch drained; all waves done with old slots

    // ---- prefetch chunk ch+1: W1 -> slot (ch+1)&1, W2 -> slot (ch+1)%3 ----
    if (ch + 1 < NCH) {
      const size_t co = (size_t)(ch + 1) * 16384;
      unsigned char* d1 = smem + 49152 + ((ch + 1) & 1) * 16384;
      unsigned char* d2 = smem + ((ch + 1) % 3) * 16384;
      gl_lds16(w_in8p + co + wv * 2048 + lane * 16, d1 + wv * 2048);
      gl_lds16(w_in8p + co + wv * 2048 + 1024 + lane * 16, d1 + wv * 2048 + 1024);
      gl_lds16(w_out8p + co + wv * 2048 + lane * 16, d2 + wv * 2048);
      gl_lds16(w_out8p + co + wv * 2048 + 1024 + lane * 16, d2 + wv * 2048 + 1024);
    }

    __builtin_amdgcn_s_setprio(1);
    // ---- GEMM2(ch-1): 32 MFMAs, 16 independent 2-chains ----
    if (ch) {
      const unsigned char* W2 = smem + ((ch - 1) % 3) * 16384;
      #pragma unroll
      for (int ct = 0; ct < 16; ++ct) {
        i64 b20 = *(const i64*)&W2[(ct * 2) * 512 + lane * 8];
        i64 b21 = *(const i64*)&W2[(ct * 2 + 1) * 512 + lane * 8];
        acc2[ct] = __builtin_amdgcn_mfma_f32_16x16x32_fp8_fp8(a2p0, b20, acc2[ct], 0, 0, 0);
        acc2[ct] = __builtin_amdgcn_mfma_f32_16x16x32_fp8_fp8(a2p1, b21, acc2[ct], 0, 0, 0);
      }
    }

    // ---- GEMM1(ch): D1[64m x 16p], K=256; 32 MFMAs, 4 independent chains ----
    const unsigned char* W1 = smem + 49152 + (ch & 1) * 16384;
    f32x4 acc1[4] = {};
    #pragma unroll
    for (int kk = 0; kk < 8; ++kk) {
      #pragma unroll
      for (int mt = 0; mt < 4; ++mt) {
        i64 a = *(const i64*)&W1[(mt * 8 + kk) * 512 + lane * 8];
        acc1[mt] = __builtin_amdgcn_mfma_f32_16x16x32_fp8_fp8(a, breg[kk], acc1[mt], 0, 0, 0);
      }
    }
    __builtin_amdgcn_s_setprio(0);

    // ---- GELU + in-register transpose, per 32m half; consumed next iter ----
    #pragma unroll
    for (int h = 0; h < 2; ++h) {
      int pk0, pk1;
      #pragma unroll
      for (int mtl = 0; mtl < 2; ++mtl) {
        const float4 bi = *(const float4*)&b_in[ch * 64 + h * 32 + mtl * 16 + l4 * 4];
        const f32x4 A = acc1[h * 2 + mtl];
        float g[4];
        #pragma unroll
        for (int r = 0; r < 4; ++r) {
          float t = A[r] + ((const float*)&bi)[r];
          g[r] = t * __builtin_amdgcn_rcpf(1.0f + __expf(-1.702f * t));
        }
        int pk = __builtin_amdgcn_cvt_pk_fp8_f32(g[0], g[1], 0, false);
        pk = __builtin_amdgcn_cvt_pk_fp8_f32(g[2], g[3], pk, true);
        if (mtl == 0) pk0 = pk; else pk1 = pk;
      }
      // writer lane (l15,l4w) holds T[p=strip+l15][m=h*32+mtl*16+l4w*4..+3];
      // reader lane (l15,l4) needs m_local = l4*8+j within the 32m half.
      const int sl = l15 + 32 * (l4 & 1);
      int v0a = __shfl(pk0, sl), v0b = __shfl(pk1, sl);
      int v1a = __shfl(pk0, sl + 16), v1b = __shfl(pk1, sl + 16);
      int vlo = (l4 & 2) ? v0b : v0a;
      int vhi = (l4 & 2) ? v1b : v1a;
      i64 a2n = (i64)((((unsigned long long)(unsigned)vhi) << 32) | (unsigned)vlo);
      if (h == 0) a2p0 = a2n; else a2p1 = a2n;
    }
  }

  // ---- drain GEMM2 for last chunk (slot (NCH-1)%3 = 0, intact) ----
  {
    const unsigned char* W2 = smem + ((NCH - 1) % 3) * 16384;
    #pragma unroll
    for (int ct = 0; ct < 16; ++ct) {
      i64 b20 = *(const i64*)&W2[(ct * 2) * 512 + lane * 8];
      i64 b21 = *(const i64*)&W2[(ct * 2 + 1) * 512 + lane * 8];
      acc2[ct] = __builtin_amdgcn_mfma_f32_16x16x32_fp8_fp8(a2p0, b20, acc2[ct], 0, 0, 0);
      acc2[ct] = __builtin_amdgcn_mfma_f32_16x16x32_fp8_fp8(a2p1, b21, acc2[ct], 0, 0, 0);
    }
  }

  // ---- epilogue: out = x + gamma_c * (v + b_out_c) ----
  #pragma unroll
  for (int ct = 0; ct < 16; ++ct) {
    int cc = ct * 16 + l15;
    float gm = gamma[cc], bo = b_out[cc];
    int p = p0 + strip + l4 * 4;
    size_t off = xbase + (size_t)cc * HW + p;
    float4 xv = *(const float4*)(x + off);
    float4 o;
    #pragma unroll
    for (int r = 0; r < 4; ++r)
      ((float*)&o)[r] = ((const float*)&xv)[r] + gm * (acc2[ct][r] + bo);
    *(float4*)(out + off) = o;
  }
}

extern "C" void kernel_launch(void* const* d_in, const int* in_sizes, int n_in,
                              void* d_out, int out_size, void* d_ws, size_t ws_size,
                              hipStream_t stream) {
  const float* x = (const float*)d_in[0];
  const float* ln_w = (const float*)d_in[1];
  const float* ln_b = (const float*)d_in[2];
  const float* w_in = (const float*)d_in[3];
  const float* b_in = (const float*)d_in[4];
  const float* w_out = (const float*)d_in[5];
  const float* b_out = (const float*)d_in[6];
  const float* gamma = (const float*)d_in[7];
  float* out = (float*)d_out;

  char* ws = (char*)d_ws;
  unsigned char* w_in8p = (unsigned char*)ws;              // 256 KB frag-packed
  unsigned char* w_out8p = (unsigned char*)(ws + 262144);  // 256 KB frag-packed
  double* partial = (double*)(ws + 524288);                // 8 KB
  float* stats = (float*)(ws + 524288 + 8192);             // 512 B

  k_prep<<<512, 256, 0, stream>>>(w_in, w_out, w_in8p, w_out8p);
  k_stats1<<<512, 256, 0, stream>>>(x, partial);
  k_stats2<<<1, 64, 0, stream>>>(partial, stats);

  const int lds_bytes = 81920;  // 80KB: exactly 2 blocks/CU
  hipFuncSetAttribute((const void*)k_fused, hipFuncAttributeMaxDynamicSharedMemorySize,
                      lds_bytes);
  k_fused<<<1024, 512, lds_bytes, stream>>>(x, ln_w, ln_b, b_in, b_out, gamma,
                                            w_in8p, w_out8p, stats, out);
}

// Round 12
// 176.745 us; speedup vs baseline: 1.0832x; 1.0832x over previous
//
#include <hip/hip_runtime.h>
#include <math.h>

// x: (4,16,256,32,64) f32 -> NS=64 samples, CD=256 channels, HW=2048 positions
#define NS 64
#define CD 256
#define HW 2048
#define MD 1024
#define SAMPLE (CD * HW)
#define LN_EPS 1e-5f

#define PB 64            // positions per block (4 pair-strips x 16p)
#define MC 32            // m-chunk
#define NCH (MD / MC)    // 32 chunks

typedef float f32x4 __attribute__((ext_vector_type(4)));
typedef long i64;

// Rotated 4-bit XOR swizzle for Ysh (bits 3-6).
__device__ __forceinline__ int swz(int p) {
  int k = (p ^ (p >> 2)) & 15;
  return ((k & 7) << 4) | (k & 8);
}

__device__ __forceinline__ void gl_lds16(const unsigned char* g, unsigned char* l) {
  __builtin_amdgcn_global_load_lds(
      (const __attribute__((address_space(1))) unsigned char*)g,
      (__attribute__((address_space(3))) unsigned char*)l, 16, 0, 0);
}

// ---------------- weight prep: f32 -> fp8 e4m3, FRAGMENT-PACKED (MC=32) ----------------
// (identical to r10) w_in8p frag f=ch*16+mt*8+kk; w_out8p frag g=ch*16+ct.
__global__ __launch_bounds__(256) void k_prep(const float* __restrict__ w_in,
                                              const float* __restrict__ w_out,
                                              unsigned char* __restrict__ w_in8p,
                                              unsigned char* __restrict__ w_out8p) {
  int id = blockIdx.x * 256 + threadIdx.x;  // 0..131071 (one int = 4 bytes each)
  if (id < 65536) {
    int i = id;
    int f = i >> 7, l = (i >> 1) & 63, j0 = (i & 1) * 4;
    int m = (f >> 3) * 16 + (l & 15);
    int c0 = (f & 7) * 32 + (l >> 4) * 8 + j0;
    float a = w_in[(size_t)(c0 + 0) * MD + m];
    float b = w_in[(size_t)(c0 + 1) * MD + m];
    float c = w_in[(size_t)(c0 + 2) * MD + m];
    float d = w_in[(size_t)(c0 + 3) * MD + m];
    int r = __builtin_amdgcn_cvt_pk_fp8_f32(a, b, 0, false);
    r = __builtin_amdgcn_cvt_pk_fp8_f32(c, d, r, true);
    ((int*)w_in8p)[i] = r;
  } else {
    int i = id - 65536;
    int g = i >> 7, l = (i >> 1) & 63, j0 = (i & 1) * 4;
    int c = (g & 15) * 16 + (l & 15);
    int m0 = (g >> 4) * 32 + (l >> 4) * 8 + j0;
    float a = w_out[(size_t)(m0 + 0) * CD + c];
    float b = w_out[(size_t)(m0 + 1) * CD + c];
    float cc = w_out[(size_t)(m0 + 2) * CD + c];
    float d = w_out[(size_t)(m0 + 3) * CD + c];
    int r = __builtin_amdgcn_cvt_pk_fp8_f32(a, b, 0, false);
    r = __builtin_amdgcn_cvt_pk_fp8_f32(cc, d, r, true);
    ((int*)w_out8p)[i] = r;
  }
}

// ---------------- LN stats, stage 1 ----------------
__global__ __launch_bounds__(256) void k_stats1(const float* __restrict__ x,
                                                double* __restrict__ partial) {
  int s = blockIdx.x >> 3, sl = blockIdx.x & 7;
  const float4* p = (const float4*)(x + (size_t)s * SAMPLE + (size_t)sl * 65536);
  double sum = 0.0, ssq = 0.0;
  for (int i = 0; i < 64; ++i) {
    float4 v = p[i * 256 + threadIdx.x];
    sum += (double)v.x + (double)v.y + (double)v.z + (double)v.w;
    ssq += (double)v.x * v.x + (double)v.y * v.y + (double)v.z * v.z + (double)v.w * v.w;
  }
  for (int off = 32; off; off >>= 1) {
    sum += __shfl_down(sum, off);
    ssq += __shfl_down(ssq, off);
  }
  __shared__ double red[4][2];
  int wv = threadIdx.x >> 6, ln = threadIdx.x & 63;
  if (ln == 0) { red[wv][0] = sum; red[wv][1] = ssq; }
  __syncthreads();
  if (threadIdx.x == 0) {
    for (int i = 1; i < 4; ++i) { sum += red[i][0]; ssq += red[i][1]; }
    partial[blockIdx.x * 2] = sum;
    partial[blockIdx.x * 2 + 1] = ssq;
  }
}

// ---------------- LN stats, stage 2 ----------------
__global__ void k_stats2(const double* __restrict__ partial, float* __restrict__ stats) {
  int s = threadIdx.x;  // 64 threads
  double sum = 0.0, ssq = 0.0;
  for (int i = 0; i < 8; ++i) {
    sum += partial[(s * 8 + i) * 2];
    ssq += partial[(s * 8 + i) * 2 + 1];
  }
  double mean = sum / (double)SAMPLE;
  double var = ssq / (double)SAMPLE - mean * mean;
  stats[s * 2] = (float)mean;
  stats[s * 2 + 1] = (float)(1.0 / sqrt(var + (double)LN_EPS));
}

// ---------------- fused LN + MLP + layer-scale + residual ----------------
// PB=64, 512 thr / 8 waves = 4 p-strips x 2 c-halves. Pair (q) owns strip
// [16q,16q+16); half h owns c [128h,128h+128) and GEMM1 m-half [16h,16h+16).
// acc2 = 32 AGPR (halved vs r10) -> ~80 unified regs -> launch_bounds(512,6)
// -> 3 blocks/CU (24 waves/CU). T handoff across the pair via 512B LDS
// exchange, write -> chunk barrier -> read (fenced; r7 lesson). Deferred
// GEMM2 (r10 pipeline). LDS 44K: [0,24K) W2 x3 | [24K,40K) W1 x2 |
// [40K,44K) Texch x2; Ysh 16K overlaid on W2 slots 1-2 (r11 protocol).
__global__ __launch_bounds__(512, 6) void k_fused(
    const float* __restrict__ x, const float* __restrict__ ln_w, const float* __restrict__ ln_b,
    const float* __restrict__ b_in, const float* __restrict__ b_out, const float* __restrict__ gamma,
    const unsigned char* __restrict__ w_in8p, const unsigned char* __restrict__ w_out8p,
    const float* __restrict__ stats, float* __restrict__ out) {
  __shared__ unsigned char smem[45056];   // 44K
  unsigned char* Ysh = smem + 8192;       // [64][256] fp8 swizzled (staging only)

  const int tid = threadIdx.x;
  const int lane = tid & 63, l15 = lane & 15, l4 = lane >> 4;
  const int wv = tid >> 6;                 // 0..7
  const int q = wv >> 1, h = wv & 1;       // pair, c/m half
  const int s = blockIdx.x >> 5;
  const int p0 = (blockIdx.x & 31) * PB;
  const float mu = stats[s * 2], rstd = stats[s * 2 + 1];
  const float a_ln = rstd, c_ln = -mu * rstd;
  const size_t xbase = (size_t)s * SAMPLE;

  // ---- prefetch chunk-0 weights into non-Ysh slots (hide under staging) ----
  gl_lds16(w_in8p + wv * 1024 + lane * 16, smem + 24576 + wv * 1024);   // W1 slot0
  gl_lds16(w_out8p + wv * 1024 + lane * 16, smem + wv * 1024);          // W2 slot0

  // ---- stage Ysh: normalize + affine, transpose (c,p)->(p,c), cvt fp8 ----
  #pragma unroll
  for (int it = 0; it < 2; ++it) {
    int bid = it * 512 + tid;               // 1024 4x4 micro-blocks
    int c0 = (bid >> 4) * 4, pp = (bid & 15) * 4;
    float yv[4][4];
    #pragma unroll
    for (int i = 0; i < 4; ++i) {
      size_t off = (size_t)(c0 + i) * HW + p0 + pp;
      float4 xv = *(const float4*)(x + xbase + off);
      float4 lw = *(const float4*)(ln_w + off);
      float4 lb = *(const float4*)(ln_b + off);
      yv[i][0] = fmaf(fmaf(xv.x, a_ln, c_ln), lw.x, lb.x);
      yv[i][1] = fmaf(fmaf(xv.y, a_ln, c_ln), lw.y, lb.y);
      yv[i][2] = fmaf(fmaf(xv.z, a_ln, c_ln), lw.z, lb.z);
      yv[i][3] = fmaf(fmaf(xv.w, a_ln, c_ln), lw.w, lb.w);
    }
    #pragma unroll
    for (int j = 0; j < 4; ++j) {
      int p = pp + j;
      int r = __builtin_amdgcn_cvt_pk_fp8_f32(yv[0][j], yv[1][j], 0, false);
      r = __builtin_amdgcn_cvt_pk_fp8_f32(yv[2][j], yv[3][j], r, true);
      *(int*)&Ysh[p * 256 + (c0 ^ swz(p))] = r;
    }
  }

  const int strip = q * 16;                // pair's p-strip
  const int pY = strip + l15;              // Ysh row this lane reads
  const int sY = swz(pY);
  f32x4 acc2[8] = {};                      // 16p x 128c per wave (8 c-tiles)

  __syncthreads();  // Ysh visible; chunk-0 weight DMA drained

  // ---- breg: the pair's ENTIRE Ysh slice -> 8 i64 registers (both halves) ----
  i64 breg[8];
  #pragma unroll
  for (int kk = 0; kk < 8; ++kk)
    breg[kk] = *(const i64*)&Ysh[pY * 256 + ((kk * 32 + l4 * 8) ^ sY)];

  __syncthreads();  // all breg reads done -> Ysh region reusable by DMA

  for (int ch = 0; ch < NCH; ++ch) {
    if (ch) __syncthreads();  // prefetch(ch) drained; old slots free; Texch(ch-1) visible

    // ---- prefetch chunk ch+1: W1 -> slot (ch+1)&1, W2 -> slot (ch+1)%3 ----
    if (ch + 1 < NCH) {
      const size_t co = (size_t)(ch + 1) * 8192;
      gl_lds16(w_in8p + co + wv * 1024 + lane * 16,
               smem + 24576 + ((ch + 1) & 1) * 8192 + wv * 1024);
      gl_lds16(w_out8p + co + wv * 1024 + lane * 16,
               smem + ((ch + 1) % 3) * 8192 + wv * 1024);
    }

    __builtin_amdgcn_s_setprio(1);
    // ---- GEMM2(ch-1): 8 MFMAs on this wave's c-half ----
    if (ch) {
      const i64 a2 = *(const i64*)(smem + 40960 + ((ch - 1) & 1) * 2048 +
                                   q * 512 + l15 * 32 + l4 * 8);
      const unsigned char* W2 = smem + ((ch - 1) % 3) * 8192;
      #pragma unroll
      for (int cti = 0; cti < 8; ++cti) {
        i64 b2 = *(const i64*)&W2[(h * 8 + cti) * 512 + lane * 8];
        acc2[cti] = __builtin_amdgcn_mfma_f32_16x16x32_fp8_fp8(a2, b2, acc2[cti], 0, 0, 0);
      }
    }

    // ---- GEMM1(ch): this wave's 16m half x pair strip 16p, K=256 ----
    const unsigned char* W1 = smem + 24576 + (ch & 1) * 8192;
    f32x4 acc1 = {};
    #pragma unroll
    for (int kk = 0; kk < 8; ++kk) {
      i64 a = *(const i64*)&W1[(h * 8 + kk) * 512 + lane * 8];
      acc1 = __builtin_amdgcn_mfma_f32_16x16x32_fp8_fp8(a, breg[kk], acc1, 0, 0, 0);
    }
    __builtin_amdgcn_s_setprio(0);

    // ---- GELU (this half's 16m) -> packed fp8 int -> Texch slot ch&1 ----
    {
      const float4 bi = *(const float4*)&b_in[ch * 32 + h * 16 + l4 * 4];
      float g[4];
      #pragma unroll
      for (int r = 0; r < 4; ++r) {
        float t = acc1[r] + ((const float*)&bi)[r];
        g[r] = t * __builtin_amdgcn_rcpf(1.0f + __expf(-1.702f * t));
      }
      int pk = __builtin_amdgcn_cvt_pk_fp8_f32(g[0], g[1], 0, false);
      pk = __builtin_amdgcn_cvt_pk_fp8_f32(g[2], g[3], pk, true);
      // T_pair[p=l15][m]: byte = q*512 + l15*32 + m; this lane: m = h*16+l4*4
      *(int*)(smem + 40960 + (ch & 1) * 2048 + q * 512 + l15 * 32 + h * 16 + l4 * 4) = pk;
    }
  }

  // ---- drain GEMM2 for last chunk (Texch written this iter -> barrier first) ----
  __syncthreads();
  {
    const i64 a2 = *(const i64*)(smem + 40960 + ((NCH - 1) & 1) * 2048 +
                                 q * 512 + l15 * 32 + l4 * 8);
    const unsigned char* W2 = smem + ((NCH - 1) % 3) * 8192;
    #pragma unroll
    for (int cti = 0; cti < 8; ++cti) {
      i64 b2 = *(const i64*)&W2[(h * 8 + cti) * 512 + lane * 8];
      acc2[cti] = __builtin_amdgcn_mfma_f32_16x16x32_fp8_fp8(a2, b2, acc2[cti], 0, 0, 0);
    }
  }

  // ---- epilogue: out = x + gamma_c * (v + b_out_c) ----
  #pragma unroll
  for (int cti = 0; cti < 8; ++cti) {
    int cc = h * 128 + cti * 16 + l15;
    float gm = gamma[cc], bo = b_out[cc];
    int p = p0 + strip + l4 * 4;
    size_t off = xbase + (size_t)cc * HW + p;
    float4 xv = *(const float4*)(x + off);
    float4 o;
    #pragma unroll
    for (int r = 0; r < 4; ++r)
      ((float*)&o)[r] = ((const float*)&xv)[r] + gm * (acc2[cti][r] + bo);
    *(float4*)(out + off) = o;
  }
}

extern "C" void kernel_launch(void* const* d_in, const int* in_sizes, int n_in,
                              void* d_out, int out_size, void* d_ws, size_t ws_size,
                              hipStream_t stream) {
  const float* x = (const float*)d_in[0];
  const float* ln_w = (const float*)d_in[1];
  const float* ln_b = (const float*)d_in[2];
  const float* w_in = (const float*)d_in[3];
  const float* b_in = (const float*)d_in[4];
  const float* w_out = (const float*)d_in[5];
  const float* b_out = (const float*)d_in[6];
  const float* gamma = (const float*)d_in[7];
  float* out = (float*)d_out;

  char* ws = (char*)d_ws;
  unsigned char* w_in8p = (unsigned char*)ws;              // 256 KB frag-packed
  unsigned char* w_out8p = (unsigned char*)(ws + 262144);  // 256 KB frag-packed
  double* partial = (double*)(ws + 524288);                // 8 KB
  float* stats = (float*)(ws + 524288 + 8192);             // 512 B

  k_prep<<<512, 256, 0, stream>>>(w_in, w_out, w_in8p, w_out8p);
  k_stats1<<<512, 256, 0, stream>>>(x, partial);
  k_stats2<<<1, 64, 0, stream>>>(partial, stats);

  k_fused<<<2048, 512, 0, stream>>>(x, ln_w, ln_b, b_in, b_out, gamma,
                                    w_in8p, w_out8p, stats, out);
}

// Round 13
// 173.781 us; speedup vs baseline: 1.1017x; 1.0171x over previous
//
#include <hip/hip_runtime.h>
#include <math.h>

// x: (4,16,256,32,64) f32 -> NS=64 samples, CD=256 channels, HW=2048 positions
#define NS 64
#define CD 256
#define HW 2048
#define MD 1024
#define SAMPLE (CD * HW)
#define LN_EPS 1e-5f

#define PB 64            // positions per block (4 pair-strips x 16p)
#define MC 32            // m-chunk
#define NCH (MD / MC)    // 32 chunks

typedef float f32x4 __attribute__((ext_vector_type(4)));
typedef long i64;

// Rotated 4-bit XOR swizzle for Ysh (bits 3-6).
__device__ __forceinline__ int swz(int p) {
  int k = (p ^ (p >> 2)) & 15;
  return ((k & 7) << 4) | (k & 8);
}

__device__ __forceinline__ void gl_lds16(const unsigned char* g, unsigned char* l) {
  __builtin_amdgcn_global_load_lds(
      (const __attribute__((address_space(1))) unsigned char*)g,
      (__attribute__((address_space(3))) unsigned char*)l, 16, 0, 0);
}

// ------------- merged: weight prep (fp8 frag-packed) + LN stats stage 1 -------------
// blocks 0..511: stats1 slices; blocks 512..1023: prep (r10/r12 fragment layout).
__global__ __launch_bounds__(256) void k_prep_stats(
    const float* __restrict__ x, const float* __restrict__ w_in,
    const float* __restrict__ w_out, unsigned char* __restrict__ w_in8p,
    unsigned char* __restrict__ w_out8p, double* __restrict__ partial) {
  if (blockIdx.x < 512) {
    int s = blockIdx.x >> 3, sl = blockIdx.x & 7;
    const float4* p = (const float4*)(x + (size_t)s * SAMPLE + (size_t)sl * 65536);
    double sum = 0.0, ssq = 0.0;
    for (int i = 0; i < 64; ++i) {
      float4 v = p[i * 256 + threadIdx.x];
      sum += (double)v.x + (double)v.y + (double)v.z + (double)v.w;
      ssq += (double)v.x * v.x + (double)v.y * v.y + (double)v.z * v.z + (double)v.w * v.w;
    }
    for (int off = 32; off; off >>= 1) {
      sum += __shfl_down(sum, off);
      ssq += __shfl_down(ssq, off);
    }
    __shared__ double red[4][2];
    int wv = threadIdx.x >> 6, ln = threadIdx.x & 63;
    if (ln == 0) { red[wv][0] = sum; red[wv][1] = ssq; }
    __syncthreads();
    if (threadIdx.x == 0) {
      for (int i = 1; i < 4; ++i) { sum += red[i][0]; ssq += red[i][1]; }
      partial[blockIdx.x * 2] = sum;
      partial[blockIdx.x * 2 + 1] = ssq;
    }
  } else {
    int id = (blockIdx.x - 512) * 256 + threadIdx.x;  // 0..131071
    if (id < 65536) {
      int i = id;
      int f = i >> 7, l = (i >> 1) & 63, j0 = (i & 1) * 4;
      int m = (f >> 3) * 16 + (l & 15);
      int c0 = (f & 7) * 32 + (l >> 4) * 8 + j0;
      float a = w_in[(size_t)(c0 + 0) * MD + m];
      float b = w_in[(size_t)(c0 + 1) * MD + m];
      float c = w_in[(size_t)(c0 + 2) * MD + m];
      float d = w_in[(size_t)(c0 + 3) * MD + m];
      int r = __builtin_amdgcn_cvt_pk_fp8_f32(a, b, 0, false);
      r = __builtin_amdgcn_cvt_pk_fp8_f32(c, d, r, true);
      ((int*)w_in8p)[i] = r;
    } else {
      int i = id - 65536;
      int g = i >> 7, l = (i >> 1) & 63, j0 = (i & 1) * 4;
      int c = (g & 15) * 16 + (l & 15);
      int m0 = (g >> 4) * 32 + (l >> 4) * 8 + j0;
      float a = w_out[(size_t)(m0 + 0) * CD + c];
      float b = w_out[(size_t)(m0 + 1) * CD + c];
      float cc = w_out[(size_t)(m0 + 2) * CD + c];
      float d = w_out[(size_t)(m0 + 3) * CD + c];
      int r = __builtin_amdgcn_cvt_pk_fp8_f32(a, b, 0, false);
      r = __builtin_amdgcn_cvt_pk_fp8_f32(cc, d, r, true);
      ((int*)w_out8p)[i] = r;
    }
  }
}

// ---------------- LN stats, stage 2 ----------------
__global__ void k_stats2(const double* __restrict__ partial, float* __restrict__ stats) {
  int s = threadIdx.x;  // 64 threads
  double sum = 0.0, ssq = 0.0;
  for (int i = 0; i < 8; ++i) {
    sum += partial[(s * 8 + i) * 2];
    ssq += partial[(s * 8 + i) * 2 + 1];
  }
  double mean = sum / (double)SAMPLE;
  double var = ssq / (double)SAMPLE - mean * mean;
  stats[s * 2] = (float)mean;
  stats[s * 2 + 1] = (float)(1.0 / sqrt(var + (double)LN_EPS));
}

// ---------------- fused LN + MLP + layer-scale + residual ----------------
// r12 structure (PB=64, 8 waves = 4 p-strips x 2 c-halves, 3 blocks/CU) with:
//  (1) GEMM1 two-chain K-split (post-barrier MFMA ILP x2),
//  (2) iteration order: a2-read -> GEMM1 -> GELU+Texch-write -> GEMM2 -> bar
//      (GELU mid-iteration; MFMA burst is the pre-barrier tail),
//  (3) Texch XOR swizzle ((blk^(l15>>2))<<3): reader 2-way (free), writer 0-way.
__global__ __launch_bounds__(512, 6) void k_fused(
    const float* __restrict__ x, const float* __restrict__ ln_w, const float* __restrict__ ln_b,
    const float* __restrict__ b_in, const float* __restrict__ b_out, const float* __restrict__ gamma,
    const unsigned char* __restrict__ w_in8p, const unsigned char* __restrict__ w_out8p,
    const float* __restrict__ stats, float* __restrict__ out) {
  __shared__ unsigned char smem[45056];   // 44K
  unsigned char* Ysh = smem + 8192;       // [64][256] fp8 swizzled (staging only)

  const int tid = threadIdx.x;
  const int lane = tid & 63, l15 = lane & 15, l4 = lane >> 4;
  const int wv = tid >> 6;                 // 0..7
  const int q = wv >> 1, h = wv & 1;       // pair, c/m half
  const int s = blockIdx.x >> 5;
  const int p0 = (blockIdx.x & 31) * PB;
  const float mu = stats[s * 2], rstd = stats[s * 2 + 1];
  const float a_ln = rstd, c_ln = -mu * rstd;
  const size_t xbase = (size_t)s * SAMPLE;

  // ---- prefetch chunk-0 weights into non-Ysh slots (hide under staging) ----
  gl_lds16(w_in8p + wv * 1024 + lane * 16, smem + 24576 + wv * 1024);   // W1 slot0
  gl_lds16(w_out8p + wv * 1024 + lane * 16, smem + wv * 1024);          // W2 slot0

  // ---- stage Ysh: normalize + affine, transpose (c,p)->(p,c), cvt fp8 ----
  #pragma unroll
  for (int it = 0; it < 2; ++it) {
    int bid = it * 512 + tid;               // 1024 4x4 micro-blocks
    int c0 = (bid >> 4) * 4, pp = (bid & 15) * 4;
    float yv[4][4];
    #pragma unroll
    for (int i = 0; i < 4; ++i) {
      size_t off = (size_t)(c0 + i) * HW + p0 + pp;
      float4 xv = *(const float4*)(x + xbase + off);
      float4 lw = *(const float4*)(ln_w + off);
      float4 lb = *(const float4*)(ln_b + off);
      yv[i][0] = fmaf(fmaf(xv.x, a_ln, c_ln), lw.x, lb.x);
      yv[i][1] = fmaf(fmaf(xv.y, a_ln, c_ln), lw.y, lb.y);
      yv[i][2] = fmaf(fmaf(xv.z, a_ln, c_ln), lw.z, lb.z);
      yv[i][3] = fmaf(fmaf(xv.w, a_ln, c_ln), lw.w, lb.w);
    }
    #pragma unroll
    for (int j = 0; j < 4; ++j) {
      int p = pp + j;
      int r = __builtin_amdgcn_cvt_pk_fp8_f32(yv[0][j], yv[1][j], 0, false);
      r = __builtin_amdgcn_cvt_pk_fp8_f32(yv[2][j], yv[3][j], r, true);
      *(int*)&Ysh[p * 256 + (c0 ^ swz(p))] = r;
    }
  }

  const int strip = q * 16;                // pair's p-strip
  const int pY = strip + l15;              // Ysh row this lane reads
  const int sY = swz(pY);
  f32x4 acc2[8] = {};                      // 16p x 128c per wave (8 c-tiles)

  __syncthreads();  // Ysh visible; chunk-0 weight DMA drained

  // ---- breg: the pair's ENTIRE Ysh slice -> 8 i64 registers ----
  i64 breg[8];
  #pragma unroll
  for (int kk = 0; kk < 8; ++kk)
    breg[kk] = *(const i64*)&Ysh[pY * 256 + ((kk * 32 + l4 * 8) ^ sY)];

  __syncthreads();  // all breg reads done -> Ysh region reusable by DMA

  // Texch addressing (swizzled): writer m-block = h*2 (per half-wave), off l4*4&7
  const int exw = ((((h * 16 + l4 * 4) >> 3) ^ (l15 >> 2)) << 3) + ((l4 & 1) * 4);
  const int exw_off = 40960 + q * 512 + l15 * 32 + exw;
  const int exr_off = 40960 + q * 512 + l15 * 32 + ((l4 ^ (l15 >> 2)) << 3);

  for (int ch = 0; ch < NCH; ++ch) {
    if (ch) __syncthreads();  // prefetch(ch) drained; old slots free; Texch(ch-1) visible

    // ---- prefetch chunk ch+1: W1 -> slot (ch+1)&1, W2 -> slot (ch+1)%3 ----
    if (ch + 1 < NCH) {
      const size_t co = (size_t)(ch + 1) * 8192;
      gl_lds16(w_in8p + co + wv * 1024 + lane * 16,
               smem + 24576 + ((ch + 1) & 1) * 8192 + wv * 1024);
      gl_lds16(w_out8p + co + wv * 1024 + lane * 16,
               smem + ((ch + 1) % 3) * 8192 + wv * 1024);
    }

    // ---- issue a2 read early (T(ch-1), visible since barrier) ----
    i64 a2 = 0;
    if (ch) a2 = *(const i64*)(smem + ((ch - 1) & 1) * 2048 + exr_off);

    // ---- GEMM1(ch): two independent K-chains ----
    const unsigned char* W1 = smem + 24576 + (ch & 1) * 8192;
    f32x4 acc1a = {}, acc1b = {};
    __builtin_amdgcn_s_setprio(1);
    #pragma unroll
    for (int kk = 0; kk < 4; ++kk) {
      i64 a = *(const i64*)&W1[(h * 8 + kk) * 512 + lane * 8];
      i64 b = *(const i64*)&W1[(h * 8 + 4 + kk) * 512 + lane * 8];
      acc1a = __builtin_amdgcn_mfma_f32_16x16x32_fp8_fp8(a, breg[kk], acc1a, 0, 0, 0);
      acc1b = __builtin_amdgcn_mfma_f32_16x16x32_fp8_fp8(b, breg[4 + kk], acc1b, 0, 0, 0);
    }
    __builtin_amdgcn_s_setprio(0);

    // ---- GELU (sum the chains) -> packed fp8 -> Texch slot ch&1 (swizzled) ----
    {
      const float4 bi = *(const float4*)&b_in[ch * 32 + h * 16 + l4 * 4];
      float g[4];
      #pragma unroll
      for (int r = 0; r < 4; ++r) {
        float t = acc1a[r] + acc1b[r] + ((const float*)&bi)[r];
        g[r] = t * __builtin_amdgcn_rcpf(1.0f + __expf(-1.702f * t));
      }
      int pk = __builtin_amdgcn_cvt_pk_fp8_f32(g[0], g[1], 0, false);
      pk = __builtin_amdgcn_cvt_pk_fp8_f32(g[2], g[3], pk, true);
      *(int*)(smem + (ch & 1) * 2048 + exw_off) = pk;
    }

    // ---- GEMM2(ch-1): 8 MFMAs, the pre-barrier tail ----
    if (ch) {
      const unsigned char* W2 = smem + ((ch - 1) % 3) * 8192;
      __builtin_amdgcn_s_setprio(1);
      #pragma unroll
      for (int cti = 0; cti < 8; ++cti) {
        i64 b2 = *(const i64*)&W2[(h * 8 + cti) * 512 + lane * 8];
        acc2[cti] = __builtin_amdgcn_mfma_f32_16x16x32_fp8_fp8(a2, b2, acc2[cti], 0, 0, 0);
      }
      __builtin_amdgcn_s_setprio(0);
    }
  }

  // ---- drain GEMM2 for last chunk (Texch written this iter -> barrier first) ----
  __syncthreads();
  {
    const i64 a2 = *(const i64*)(smem + ((NCH - 1) & 1) * 2048 + exr_off);
    const unsigned char* W2 = smem + ((NCH - 1) % 3) * 8192;
    #pragma unroll
    for (int cti = 0; cti < 8; ++cti) {
      i64 b2 = *(const i64*)&W2[(h * 8 + cti) * 512 + lane * 8];
      acc2[cti] = __builtin_amdgcn_mfma_f32_16x16x32_fp8_fp8(a2, b2, acc2[cti], 0, 0, 0);
    }
  }

  // ---- epilogue: out = x + gamma_c * (v + b_out_c) ----
  #pragma unroll
  for (int cti = 0; cti < 8; ++cti) {
    int cc = h * 128 + cti * 16 + l15;
    float gm = gamma[cc], bo = b_out[cc];
    int p = p0 + strip + l4 * 4;
    size_t off = xbase + (size_t)cc * HW + p;
    float4 xv = *(const float4*)(x + off);
    float4 o;
    #pragma unroll
    for (int r = 0; r < 4; ++r)
      ((float*)&o)[r] = ((const float*)&xv)[r] + gm * (acc2[cti][r] + bo);
    *(float4*)(out + off) = o;
  }
}

extern "C" void kernel_launch(void* const* d_in, const int* in_sizes, int n_in,
                              void* d_out, int out_size, void* d_ws, size_t ws_size,
                              hipStream_t stream) {
  const float* x = (const float*)d_in[0];
  const float* ln_w = (const float*)d_in[1];
  const float* ln_b = (const float*)d_in[2];
  const float* w_in = (const float*)d_in[3];
  const float* b_in = (const float*)d_in[4];
  const float* w_out = (const float*)d_in[5];
  const float* b_out = (const float*)d_in[6];
  const float* gamma = (const float*)d_in[7];
  float* out = (float*)d_out;

  char* ws = (char*)d_ws;
  unsigned char* w_in8p = (unsigned char*)ws;              // 256 KB frag-packed
  unsigned char* w_out8p = (unsigned char*)(ws + 262144);  // 256 KB frag-packed
  double* partial = (double*)(ws + 524288);                // 8 KB
  float* stats = (float*)(ws + 524288 + 8192);             // 512 B

  k_prep_stats<<<1024, 256, 0, stream>>>(x, w_in, w_out, w_in8p, w_out8p, partial);
  k_stats2<<<1, 64, 0, stream>>>(partial, stats);

  k_fused<<<2048, 512, 0, stream>>>(x, ln_w, ln_b, b_in, b_out, gamma,
                                    w_in8p, w_out8p, stats, out);
}